// Round 6
// baseline (320.867 us; speedup 1.0000x reference)
//
#include <hip/hip_runtime.h>
#include <stdint.h>

#define NROWS 16384
#define NCODES 8192
#define DIM 256

#define BROWS 64
#define PCOLS 2048
#define BCOLS 128
#define NCITER (PCOLS / BCOLS)   // 16 citers x 4 K-chunks = 64 chunks

// workspace layout (bytes)
#define OFF_C2D   0u          // double[8192]             65536
#define OFF_PTOP  65536u      // u64[16384][4][2]       1048576
#define OFF_LSLOT 1114112u    // double[256]               2048
#define OFF_DONE  1116160u    // u32[1] (+pad)              128
#define OFF_Z16   1116288u    // u16[16384*256]         8388608
#define OFF_CB16  9504896u    // u16[8192*256]          4194304

typedef __attribute__((ext_vector_type(8))) short bf16x8;
typedef __attribute__((ext_vector_type(4))) float f32x4;

__device__ __forceinline__ uint32_t enc_f32(float f) {
  uint32_t u = __float_as_uint(f);
  return (u & 0x80000000u) ? ~u : (u | 0x80000000u);
}
__device__ __forceinline__ unsigned short f2bf(float f) {
  uint32_t u = __float_as_uint(f);
  u += 0x7fffu + ((u >> 16) & 1u);   // RNE (inputs finite)
  return (unsigned short)(u >> 16);
}
__device__ __forceinline__ void gload16(const void* g, void* l) {
  __builtin_amdgcn_global_load_lds(
      (const __attribute__((address_space(1))) unsigned int*)g,
      (__attribute__((address_space(3))) unsigned int*)l, 16, 0, 0);
}
__device__ __forceinline__ unsigned long long umin64(unsigned long long a,
                                                     unsigned long long b) {
  return a < b ? a : b;
}

// ---- kernel 1: prep — z cvt | cb cvt + fp64 norms | state init ----
__global__ __launch_bounds__(256) void k_prep(
    const float* __restrict__ z, const float* __restrict__ cb,
    unsigned short* __restrict__ z16, unsigned short* __restrict__ cb16,
    double* __restrict__ c2d, double* __restrict__ lossSlots,
    uint32_t* __restrict__ doneCnt) {
  const int bid = blockIdx.x;
  if (bid < 4096) {
    const int i = bid * 256 + threadIdx.x;
    float4 v = reinterpret_cast<const float4*>(z)[i];
    ushort4 o = {f2bf(v.x), f2bf(v.y), f2bf(v.z), f2bf(v.w)};
    reinterpret_cast<ushort4*>(z16)[i] = o;
  } else if (bid < 6144) {
    const int w = threadIdx.x >> 6, lane = threadIdx.x & 63;
    const int j = (bid - 4096) * 4 + w;
    float4 v = *reinterpret_cast<const float4*>(cb + (size_t)j * DIM + lane * 4);
    ushort4 o = {f2bf(v.x), f2bf(v.y), f2bf(v.z), f2bf(v.w)};
    *reinterpret_cast<ushort4*>(cb16 + (size_t)j * DIM + lane * 4) = o;
    double s = (double)v.x * v.x + (double)v.y * v.y +
               (double)v.z * v.z + (double)v.w * v.w;
#pragma unroll
    for (int off = 32; off > 0; off >>= 1) s += __shfl_xor(s, off);
    if (lane == 0) c2d[j] = s;
  } else {
    const int idx = (bid - 6144) * 256 + threadIdx.x;   // 0..511
    if (idx < 256) lossSlots[idx] = 0.0;
    else if (idx == 256) doneCnt[0] = 0u;
  }
}

// ---- kernel 2: panel-persistent MFMA dot-max, counted-vmcnt pipeline ----
// 1024 blocks: 4 col-panels x 256 row-panels, XCD-swizzled (panel-major ->
// each XCD's L2 holds one 1MB codebook panel). Per block: 64 rows x 2048 cols.
// 4 waves 2x2; wave = 32 rows x 64 cols. A in registers (whole K). B triple-
// buffered in LDS, stage 2 chunks ahead, s_waitcnt vmcnt(8) (never 0 in loop).
// launch_bounds min-waves/EU = 2 -> VGPR cap 256 (round-4 lesson: (256,3)
// => 170-reg cap => spill => 95 MB scratch traffic, 1.5x regression).
// Epilogue (round-6): deterministic per-(row,panel) top-2 via shfl butterfly
// + plain stores — no global atomics (replaces margin-capture; round-5 lesson:
// capture overflow made refine serial ~17 iters, 137 us).
__global__ __launch_bounds__(256, 2) void k_score(
    const unsigned short* __restrict__ z16, const unsigned short* __restrict__ cb16,
    unsigned long long* __restrict__ ptop) {
  __shared__ unsigned short pool[3 * BCOLS * 64];   // 3 x 16 KB
  __shared__ unsigned long long top_sh[BROWS][2][2];

  const int tid = threadIdx.x;
  const int lane = tid & 63;
  const int w = tid >> 6;
  const int wr = w >> 1, wc = w & 1;
  const int l15 = lane & 15, l4 = lane >> 4;

  // bijective XCD swizzle (1024 % 8 == 0), col-panel-major
  const int wg = (blockIdx.x & 7) * 128 + (blockIdx.x >> 3);
  const int panel = wg >> 8;          // 0..3
  const int row0 = (wg & 255) * BROWS;
  const int col0 = panel * PCOLS;

  // ---- A direct global -> registers (rows wr*32.., whole K) ----
  bf16x8 a_reg[2][8];
#pragma unroll
  for (int mi = 0; mi < 2; ++mi)
#pragma unroll
    for (int kt = 0; kt < 8; ++kt)
      a_reg[mi][kt] = *reinterpret_cast<const bf16x8*>(
          z16 + (size_t)(row0 + wr * 32 + mi * 16 + l15) * DIM + kt * 32 + l4 * 8);
  // Drain A-loads so in-loop vmcnt(8) counts ONLY stage loads (4/chunk).
  asm volatile("s_waitcnt vmcnt(0)" ::: "memory");
  __builtin_amdgcn_sched_barrier(0);

  // B staging constants (pre-swizzled global source; LDS stays linear).
  const int bc_loc = tid >> 3;                                         // 0..31
  const int kswz_e = ((((tid & 7) * 16) ^ (((tid >> 3) & 7) << 4)) >> 1);
  const unsigned wbase = (unsigned)w * 1024u;

#define STAGE(ci_, kc_, buf_) do {                                             \
    const unsigned short* gsrc_ = cb16 +                                       \
        (size_t)(col0 + (ci_) * BCOLS + bc_loc) * DIM + (kc_) * 64 + kswz_e;   \
    char* ldst_ = (char*)pool + (buf_) * 16384 + wbase;                        \
    gload16(gsrc_,            ldst_);                                          \
    gload16(gsrc_ + 32 * DIM, ldst_ + 4096);                                   \
    gload16(gsrc_ + 64 * DIM, ldst_ + 8192);                                   \
    gload16(gsrc_ + 96 * DIM, ldst_ + 12288);                                  \
  } while (0)

#define COMPUTE(kc_, buf_) do {                                                \
    _Pragma("unroll")                                                          \
    for (int kk_ = 0; kk_ < 2; ++kk_) {                                        \
      bf16x8 bf_[4];                                                           \
      _Pragma("unroll")                                                        \
      for (int ni_ = 0; ni_ < 4; ++ni_) {                                      \
        const int cI_ = wc * 64 + ni_ * 16 + l15;                              \
        const int kb_ = (kk_ * 64 + l4 * 16) ^ ((l15 & 7) << 4);               \
        bf_[ni_] = *reinterpret_cast<const bf16x8*>(                           \
            (const char*)pool + (buf_) * 16384 + cI_ * 128 + kb_);             \
      }                                                                        \
      _Pragma("unroll")                                                        \
      for (int mi_ = 0; mi_ < 2; ++mi_)                                        \
        _Pragma("unroll")                                                      \
        for (int ni_ = 0; ni_ < 4; ++ni_)                                      \
          acc[mi_][ni_] = __builtin_amdgcn_mfma_f32_16x16x32_bf16(             \
              a_reg[mi_][(kc_) * 2 + kk_], bf_[ni_], acc[mi_][ni_], 0, 0, 0);  \
    }                                                                          \
  } while (0)

#define CHUNK(kc_, bufR_, sci_, skc_, bufS_)                                   \
  __builtin_amdgcn_s_barrier();                                                \
  __builtin_amdgcn_sched_barrier(0);                                           \
  STAGE(sci_, skc_, bufS_);                                                    \
  asm volatile("s_waitcnt vmcnt(8)" ::: "memory");                             \
  __builtin_amdgcn_s_barrier();                                                \
  __builtin_amdgcn_sched_barrier(0);                                           \
  __builtin_amdgcn_s_setprio(1);                                               \
  COMPUTE(kc_, bufR_);                                                         \
  __builtin_amdgcn_s_setprio(0);

#define CHUNK_V4(kc_, bufR_)                                                   \
  __builtin_amdgcn_s_barrier();                                                \
  __builtin_amdgcn_sched_barrier(0);                                           \
  asm volatile("s_waitcnt vmcnt(4)" ::: "memory");                             \
  __builtin_amdgcn_s_barrier();                                                \
  __builtin_amdgcn_sched_barrier(0);                                           \
  __builtin_amdgcn_s_setprio(1);                                               \
  COMPUTE(kc_, bufR_);                                                         \
  __builtin_amdgcn_s_setprio(0);

#define CHUNK_V0(kc_, bufR_)                                                   \
  __builtin_amdgcn_s_barrier();                                                \
  __builtin_amdgcn_sched_barrier(0);                                           \
  asm volatile("s_waitcnt vmcnt(0)" ::: "memory");                             \
  __builtin_amdgcn_s_barrier();                                                \
  __builtin_amdgcn_sched_barrier(0);                                           \
  __builtin_amdgcn_s_setprio(1);                                               \
  COMPUTE(kc_, bufR_);                                                         \
  __builtin_amdgcn_s_setprio(0);

#define ZERO_ACC() do {                                                        \
    _Pragma("unroll")                                                          \
    for (int mi_ = 0; mi_ < 2; ++mi_)                                          \
      _Pragma("unroll")                                                        \
      for (int ni_ = 0; ni_ < 4; ++ni_)                                        \
        acc[mi_][ni_] = (f32x4){0.f, 0.f, 0.f, 0.f};                           \
  } while (0)

#define EPI(ci_) do {                                                          \
    const uint32_t cbase = (uint32_t)(col0 + (ci_) * BCOLS + wc * 64 + l15);   \
    _Pragma("unroll")                                                          \
    for (int mi_ = 0; mi_ < 2; ++mi_)                                          \
      _Pragma("unroll")                                                        \
      for (int q_ = 0; q_ < 4; ++q_) {                                         \
        const int s_ = mi_ * 4 + q_;                                           \
        const float d0 = acc[mi_][0][q_], d1 = acc[mi_][1][q_];                \
        const float d2 = acc[mi_][2][q_], d3 = acc[mi_][3][q_];                \
        const float m01 = fmaxf(d0, d1);                                       \
        const uint32_t c01 = d1 > d0 ? cbase + 16u : cbase;                    \
        const float m23 = fmaxf(d2, d3);                                       \
        const uint32_t c23 = d3 > d2 ? cbase + 48u : cbase + 32u;              \
        const float mv = fmaxf(m01, m23);                                      \
        const uint32_t mc = m23 > m01 ? c23 : c01;                             \
        const bool g0 = mv > b0v[s_];                                          \
        const bool g1 = mv > b1v[s_];                                          \
        b1v[s_] = g0 ? b0v[s_] : (g1 ? mv : b1v[s_]);                          \
        b1c[s_] = g0 ? b0c[s_] : (g1 ? mc : b1c[s_]);                          \
        b0v[s_] = g0 ? mv : b0v[s_];                                           \
        b0c[s_] = g0 ? mc : b0c[s_];                                           \
      }                                                                        \
  } while (0)

  f32x4 acc[2][4];
  float b0v[8], b1v[8];
  uint32_t b0c[8], b1c[8];
#pragma unroll
  for (int s = 0; s < 8; ++s) {
    b0v[s] = -1e30f; b1v[s] = -1e30f; b0c[s] = 0u; b1c[s] = 0u;
  }

  // prologue: stage chunks 0,1
  STAGE(0, 0, 0);
  STAGE(0, 1, 1);

  // main: 5 superblocks x 3 citers (buffer phase repeats every 3 citers)
  int ci = 0;
  for (int sb = 0; sb < 5; ++sb) {
    ZERO_ACC();
    CHUNK(0, 0, ci, 2, 2) CHUNK(1, 1, ci, 3, 0)
    CHUNK(2, 2, ci + 1, 0, 1) CHUNK(3, 0, ci + 1, 1, 2) EPI(ci); ++ci;
    ZERO_ACC();
    CHUNK(0, 1, ci, 2, 0) CHUNK(1, 2, ci, 3, 1)
    CHUNK(2, 0, ci + 1, 0, 2) CHUNK(3, 1, ci + 1, 1, 0) EPI(ci); ++ci;
    ZERO_ACC();
    CHUNK(0, 2, ci, 2, 1) CHUNK(1, 0, ci, 3, 2)
    CHUNK(2, 1, ci + 1, 0, 0) CHUNK(3, 2, ci + 1, 1, 1) EPI(ci); ++ci;
  }
  // tail citer 15 (phase A): stages for its own chunks 2,3 then drain
  ZERO_ACC();
  CHUNK(0, 0, 15, 2, 2) CHUNK(1, 1, 15, 3, 0)
  CHUNK_V4(2, 2) CHUNK_V0(3, 0) EPI(15);

  // ---- block end: top-2 butterfly over l15 lanes, wc-merge, plain store ----
#pragma unroll
  for (int mi = 0; mi < 2; ++mi)
#pragma unroll
    for (int q = 0; q < 4; ++q) {
      const int s = mi * 4 + q;
      unsigned long long p0 =
          ((unsigned long long)enc_f32(-2.0f * b0v[s]) << 32) | b0c[s];
      unsigned long long p1 =
          ((unsigned long long)enc_f32(-2.0f * b1v[s]) << 32) | b1c[s];
#pragma unroll
      for (int off = 1; off < 16; off <<= 1) {
        const unsigned long long o0 = __shfl_xor(p0, off);
        const unsigned long long o1 = __shfl_xor(p1, off);
        const unsigned long long hi = p0 > o0 ? p0 : o0;
        p0 = umin64(p0, o0);
        p1 = umin64(hi, umin64(p1, o1));
      }
      if (l15 == 0) {
        const int rloc = wr * 32 + mi * 16 + l4 * 4 + q;
        top_sh[rloc][wc][0] = p0;
        top_sh[rloc][wc][1] = p1;
      }
    }
  __syncthreads();
  if (tid < BROWS) {
    const unsigned long long a0 = top_sh[tid][0][0], a1 = top_sh[tid][0][1];
    const unsigned long long c0 = top_sh[tid][1][0], c1 = top_sh[tid][1][1];
    const unsigned long long hi = a0 > c0 ? a0 : c0;
    ptop[(size_t)(row0 + tid) * 8 + panel * 2 + 0] = umin64(a0, c0);
    ptop[(size_t)(row0 + tid) * 8 + panel * 2 + 1] = umin64(hi, umin64(a1, c1));
  }
#undef STAGE
#undef COMPUTE
#undef CHUNK
#undef CHUNK_V4
#undef CHUNK_V0
#undef ZERO_ACC
#undef EPI
}

// ---- kernel 3: parallel fp64 refine (8 fixed candidates) + gather + loss ----
// wave per row; 8 lane-groups of 8 each score one candidate concurrently.
__global__ __launch_bounds__(256) void k_refine_out(
    const float* __restrict__ z, const float* __restrict__ cb,
    const double* __restrict__ c2d, const unsigned long long* __restrict__ ptop,
    float* __restrict__ out, double* __restrict__ lossSlots,
    uint32_t* __restrict__ doneCnt) {
  const int w = threadIdx.x >> 6;
  const int lane = threadIdx.x & 63;
  const int r = blockIdx.x * 4 + w;
  const int g = lane >> 3;     // candidate slot 0..7 ([panel][2])
  const int u = lane & 7;

  const uint32_t jg =
      (uint32_t)(ptop[(size_t)r * 8 + g] & 0xFFFFFFFFull);

  // fp64 partial dot: lane covers elems [u*32, u*32+32)
  const float* zrow = z + (size_t)r * DIM;
  const float* crow = cb + (size_t)jg * DIM;
  double acc = 0.0;
#pragma unroll
  for (int t = 0; t < 8; ++t) {
    const float4 zv4 = *reinterpret_cast<const float4*>(zrow + u * 32 + t * 4);
    const float4 cv4 = *reinterpret_cast<const float4*>(crow + u * 32 + t * 4);
    acc += (double)zv4.x * cv4.x + (double)zv4.y * cv4.y +
           (double)zv4.z * cv4.z + (double)zv4.w * cv4.w;
  }
#pragma unroll
  for (int off = 1; off < 8; off <<= 1) acc += __shfl_xor(acc, off);
  // group leaders hold exact scores; cross-group argmin with lowest-j ties
  double s = (u == 0) ? (c2d[jg] - 2.0 * acc) : 1e300;
  uint32_t jj = (u == 0) ? jg : 0xFFFFFFFFu;
#pragma unroll
  for (int off = 8; off < 64; off <<= 1) {
    const double s2 = __shfl_xor(s, off);
    const uint32_t j2 = __shfl_xor(jj, off);
    if (s2 < s || (s2 == s && j2 < jj)) { s = s2; jj = j2; }
  }
  const uint32_t bestJ = __shfl(jj, 0);

  // gather z_q, write out, fp64 loss partial
  const float4 zv = *reinterpret_cast<const float4*>(zrow + lane * 4);
  const float4 q = *reinterpret_cast<const float4*>(
      cb + (size_t)bestJ * DIM + lane * 4);
  *reinterpret_cast<float4*>(out + (size_t)r * DIM + lane * 4) = q;
  const float dx = zv.x - q.x, dy = zv.y - q.y, dz = zv.z - q.z, dw = zv.w - q.w;
  double v = (double)dx * dx + (double)dy * dy + (double)dz * dz + (double)dw * dw;
#pragma unroll
  for (int off = 32; off > 0; off >>= 1) v += __shfl_xor(v, off);
  if (lane == 0) atomicAdd(&lossSlots[r & 255], v);

  // ---- last-block loss finalize ----
  __shared__ int lastFlag;
  __shared__ double part[4];
  __syncthreads();                       // all waves' slot-adds issued
  if (threadIdx.x == 0) {
    __threadfence();                     // make our adds visible before signal
    lastFlag = (atomicAdd(doneCnt, 1u) == (uint32_t)(gridDim.x - 1));
  }
  __syncthreads();
  if (lastFlag) {
    double sv = atomicAdd(&lossSlots[threadIdx.x], 0.0);   // coherent read
#pragma unroll
    for (int off = 32; off > 0; off >>= 1) sv += __shfl_xor(sv, off);
    if (lane == 0) part[w] = sv;
    __syncthreads();
    if (threadIdx.x == 0) {
      const double mse = (part[0] + part[1] + part[2] + part[3]) /
                         (double)((size_t)NROWS * DIM);
      out[(size_t)NROWS * DIM] = (float)(1.1 * mse);   // 0.1*mse + mse
    }
  }
}

extern "C" void kernel_launch(void* const* d_in, const int* in_sizes, int n_in,
                              void* d_out, int out_size, void* d_ws, size_t ws_size,
                              hipStream_t stream) {
  const float* z  = (const float*)d_in[0];
  const float* cb = (const float*)d_in[1];
  float* out = (float*)d_out;
  char* ws = (char*)d_ws;
  double* c2d = (double*)(ws + OFF_C2D);
  unsigned long long* ptop = (unsigned long long*)(ws + OFF_PTOP);
  double* lossSlots = (double*)(ws + OFF_LSLOT);
  uint32_t* doneCnt = (uint32_t*)(ws + OFF_DONE);
  unsigned short* z16  = (unsigned short*)(ws + OFF_Z16);
  unsigned short* cb16 = (unsigned short*)(ws + OFF_CB16);

  hipLaunchKernelGGL(k_prep, dim3(4096 + 2048 + 2), dim3(256), 0, stream,
                     z, cb, z16, cb16, c2d, lossSlots, doneCnt);
  hipLaunchKernelGGL(k_score, dim3((NROWS / BROWS) * (NCODES / PCOLS)),
                     dim3(256), 0, stream, z16, cb16, ptop);
  hipLaunchKernelGGL(k_refine_out, dim3(NROWS / 4), dim3(256), 0, stream,
                     z, cb, c2d, ptop, out, lossSlots, doneCnt);
}

// Round 7
// 200.999 us; speedup vs baseline: 1.5964x; 1.5964x over previous
//
#include <hip/hip_runtime.h>
#include <stdint.h>

#define NROWS 16384
#define NCODES 8192
#define DIM 256

#define BROWS 64
#define PCOLS 2048
#define BCOLS 128
#define NCITER (PCOLS / BCOLS)   // 16 citers x 4 K-chunks = 64 chunks

// workspace layout (bytes)
#define OFF_C2D   0u          // double[8192]             65536
#define OFF_PTOP  65536u      // u64[16384][4][2]       1048576
#define OFF_LSLOT 1114112u    // double[256]               2048
#define OFF_Z16   1116288u    // u16[16384*256]         8388608
#define OFF_CB16  9504896u    // u16[8192*256]          4194304

typedef __attribute__((ext_vector_type(8))) short bf16x8;
typedef __attribute__((ext_vector_type(4))) float f32x4;

__device__ __forceinline__ uint32_t enc_f32(float f) {
  uint32_t u = __float_as_uint(f);
  return (u & 0x80000000u) ? ~u : (u | 0x80000000u);
}
__device__ __forceinline__ unsigned short f2bf(float f) {
  uint32_t u = __float_as_uint(f);
  u += 0x7fffu + ((u >> 16) & 1u);   // RNE (inputs finite)
  return (unsigned short)(u >> 16);
}
__device__ __forceinline__ void gload16(const void* g, void* l) {
  __builtin_amdgcn_global_load_lds(
      (const __attribute__((address_space(1))) unsigned int*)g,
      (__attribute__((address_space(3))) unsigned int*)l, 16, 0, 0);
}
__device__ __forceinline__ unsigned long long umin64(unsigned long long a,
                                                     unsigned long long b) {
  return a < b ? a : b;
}

// ---- kernel 1: prep — z cvt | cb cvt + fp64 norms | loss-slot init ----
__global__ __launch_bounds__(256) void k_prep(
    const float* __restrict__ z, const float* __restrict__ cb,
    unsigned short* __restrict__ z16, unsigned short* __restrict__ cb16,
    double* __restrict__ c2d, double* __restrict__ lossSlots) {
  const int bid = blockIdx.x;
  if (bid < 4096) {
    const int i = bid * 256 + threadIdx.x;
    float4 v = reinterpret_cast<const float4*>(z)[i];
    ushort4 o = {f2bf(v.x), f2bf(v.y), f2bf(v.z), f2bf(v.w)};
    reinterpret_cast<ushort4*>(z16)[i] = o;
  } else if (bid < 6144) {
    const int w = threadIdx.x >> 6, lane = threadIdx.x & 63;
    const int j = (bid - 4096) * 4 + w;
    float4 v = *reinterpret_cast<const float4*>(cb + (size_t)j * DIM + lane * 4);
    ushort4 o = {f2bf(v.x), f2bf(v.y), f2bf(v.z), f2bf(v.w)};
    *reinterpret_cast<ushort4*>(cb16 + (size_t)j * DIM + lane * 4) = o;
    double s = (double)v.x * v.x + (double)v.y * v.y +
               (double)v.z * v.z + (double)v.w * v.w;
#pragma unroll
    for (int off = 32; off > 0; off >>= 1) s += __shfl_xor(s, off);
    if (lane == 0) c2d[j] = s;
  } else {
    lossSlots[threadIdx.x] = 0.0;
  }
}

// ---- kernel 2: panel-persistent MFMA dot-max, counted-vmcnt pipeline ----
// 1024 blocks: 4 col-panels x 256 row-panels, XCD-swizzled (panel-major ->
// each XCD's L2 holds one 1MB codebook panel). Per block: 64 rows x 2048 cols.
// 4 waves 2x2; wave = 32 rows x 64 cols. A in registers (whole K). B triple-
// buffered in LDS, stage 2 chunks ahead, s_waitcnt vmcnt(8) (never 0 in loop).
// launch_bounds min-waves/EU = 2 -> VGPR cap 256 (round-4 lesson: (256,3)
// => 170-reg cap => spill => 95 MB scratch traffic, 1.5x regression).
// Epilogue: deterministic per-(row,panel) top-2 via shfl butterfly + plain
// stores — no global atomics (round-5/6 lesson: NO device-scope fences or
// cross-block signaling inside a hot kernel; threadfence's L2 writeback
// poisoned the whole kernel, 162 us of idle).
__global__ __launch_bounds__(256, 2) void k_score(
    const unsigned short* __restrict__ z16, const unsigned short* __restrict__ cb16,
    unsigned long long* __restrict__ ptop) {
  __shared__ unsigned short pool[3 * BCOLS * 64];   // 3 x 16 KB
  __shared__ unsigned long long top_sh[BROWS][2][2];

  const int tid = threadIdx.x;
  const int lane = tid & 63;
  const int w = tid >> 6;
  const int wr = w >> 1, wc = w & 1;
  const int l15 = lane & 15, l4 = lane >> 4;

  // bijective XCD swizzle (1024 % 8 == 0), col-panel-major
  const int wg = (blockIdx.x & 7) * 128 + (blockIdx.x >> 3);
  const int panel = wg >> 8;          // 0..3
  const int row0 = (wg & 255) * BROWS;
  const int col0 = panel * PCOLS;

  // ---- A direct global -> registers (rows wr*32.., whole K) ----
  bf16x8 a_reg[2][8];
#pragma unroll
  for (int mi = 0; mi < 2; ++mi)
#pragma unroll
    for (int kt = 0; kt < 8; ++kt)
      a_reg[mi][kt] = *reinterpret_cast<const bf16x8*>(
          z16 + (size_t)(row0 + wr * 32 + mi * 16 + l15) * DIM + kt * 32 + l4 * 8);
  // Drain A-loads so in-loop vmcnt(8) counts ONLY stage loads (4/chunk).
  asm volatile("s_waitcnt vmcnt(0)" ::: "memory");
  __builtin_amdgcn_sched_barrier(0);

  // B staging constants (pre-swizzled global source; LDS stays linear).
  const int bc_loc = tid >> 3;                                         // 0..31
  const int kswz_e = ((((tid & 7) * 16) ^ (((tid >> 3) & 7) << 4)) >> 1);
  const unsigned wbase = (unsigned)w * 1024u;

#define STAGE(ci_, kc_, buf_) do {                                             \
    const unsigned short* gsrc_ = cb16 +                                       \
        (size_t)(col0 + (ci_) * BCOLS + bc_loc) * DIM + (kc_) * 64 + kswz_e;   \
    char* ldst_ = (char*)pool + (buf_) * 16384 + wbase;                        \
    gload16(gsrc_,            ldst_);                                          \
    gload16(gsrc_ + 32 * DIM, ldst_ + 4096);                                   \
    gload16(gsrc_ + 64 * DIM, ldst_ + 8192);                                   \
    gload16(gsrc_ + 96 * DIM, ldst_ + 12288);                                  \
  } while (0)

#define COMPUTE(kc_, buf_) do {                                                \
    _Pragma("unroll")                                                          \
    for (int kk_ = 0; kk_ < 2; ++kk_) {                                        \
      bf16x8 bf_[4];                                                           \
      _Pragma("unroll")                                                        \
      for (int ni_ = 0; ni_ < 4; ++ni_) {                                      \
        const int cI_ = wc * 64 + ni_ * 16 + l15;                              \
        const int kb_ = (kk_ * 64 + l4 * 16) ^ ((l15 & 7) << 4);               \
        bf_[ni_] = *reinterpret_cast<const bf16x8*>(                           \
            (const char*)pool + (buf_) * 16384 + cI_ * 128 + kb_);             \
      }                                                                        \
      _Pragma("unroll")                                                        \
      for (int mi_ = 0; mi_ < 2; ++mi_)                                        \
        _Pragma("unroll")                                                      \
        for (int ni_ = 0; ni_ < 4; ++ni_)                                      \
          acc[mi_][ni_] = __builtin_amdgcn_mfma_f32_16x16x32_bf16(             \
              a_reg[mi_][(kc_) * 2 + kk_], bf_[ni_], acc[mi_][ni_], 0, 0, 0);  \
    }                                                                          \
  } while (0)

#define CHUNK(kc_, bufR_, sci_, skc_, bufS_)                                   \
  __builtin_amdgcn_s_barrier();                                                \
  __builtin_amdgcn_sched_barrier(0);                                           \
  STAGE(sci_, skc_, bufS_);                                                    \
  asm volatile("s_waitcnt vmcnt(8)" ::: "memory");                             \
  __builtin_amdgcn_s_barrier();                                                \
  __builtin_amdgcn_sched_barrier(0);                                           \
  __builtin_amdgcn_s_setprio(1);                                               \
  COMPUTE(kc_, bufR_);                                                         \
  __builtin_amdgcn_s_setprio(0);

#define CHUNK_V4(kc_, bufR_)                                                   \
  __builtin_amdgcn_s_barrier();                                                \
  __builtin_amdgcn_sched_barrier(0);                                           \
  asm volatile("s_waitcnt vmcnt(4)" ::: "memory");                             \
  __builtin_amdgcn_s_barrier();                                                \
  __builtin_amdgcn_sched_barrier(0);                                           \
  __builtin_amdgcn_s_setprio(1);                                               \
  COMPUTE(kc_, bufR_);                                                         \
  __builtin_amdgcn_s_setprio(0);

#define CHUNK_V0(kc_, bufR_)                                                   \
  __builtin_amdgcn_s_barrier();                                                \
  __builtin_amdgcn_sched_barrier(0);                                           \
  asm volatile("s_waitcnt vmcnt(0)" ::: "memory");                             \
  __builtin_amdgcn_s_barrier();                                                \
  __builtin_amdgcn_sched_barrier(0);                                           \
  __builtin_amdgcn_s_setprio(1);                                               \
  COMPUTE(kc_, bufR_);                                                         \
  __builtin_amdgcn_s_setprio(0);

#define ZERO_ACC() do {                                                        \
    _Pragma("unroll")                                                          \
    for (int mi_ = 0; mi_ < 2; ++mi_)                                          \
      _Pragma("unroll")                                                        \
      for (int ni_ = 0; ni_ < 4; ++ni_)                                        \
        acc[mi_][ni_] = (f32x4){0.f, 0.f, 0.f, 0.f};                           \
  } while (0)

#define EPI(ci_) do {                                                          \
    const uint32_t cbase = (uint32_t)(col0 + (ci_) * BCOLS + wc * 64 + l15);   \
    _Pragma("unroll")                                                          \
    for (int mi_ = 0; mi_ < 2; ++mi_)                                          \
      _Pragma("unroll")                                                        \
      for (int q_ = 0; q_ < 4; ++q_) {                                         \
        const int s_ = mi_ * 4 + q_;                                           \
        const float d0 = acc[mi_][0][q_], d1 = acc[mi_][1][q_];                \
        const float d2 = acc[mi_][2][q_], d3 = acc[mi_][3][q_];                \
        const float m01 = fmaxf(d0, d1);                                       \
        const uint32_t c01 = d1 > d0 ? cbase + 16u : cbase;                    \
        const float m23 = fmaxf(d2, d3);                                       \
        const uint32_t c23 = d3 > d2 ? cbase + 48u : cbase + 32u;              \
        const float mv = fmaxf(m01, m23);                                      \
        const uint32_t mc = m23 > m01 ? c23 : c01;                             \
        const bool g0 = mv > b0v[s_];                                          \
        const bool g1 = mv > b1v[s_];                                          \
        b1v[s_] = g0 ? b0v[s_] : (g1 ? mv : b1v[s_]);                          \
        b1c[s_] = g0 ? b0c[s_] : (g1 ? mc : b1c[s_]);                          \
        b0v[s_] = g0 ? mv : b0v[s_];                                           \
        b0c[s_] = g0 ? mc : b0c[s_];                                           \
      }                                                                        \
  } while (0)

  f32x4 acc[2][4];
  float b0v[8], b1v[8];
  uint32_t b0c[8], b1c[8];
#pragma unroll
  for (int s = 0; s < 8; ++s) {
    b0v[s] = -1e30f; b1v[s] = -1e30f; b0c[s] = 0u; b1c[s] = 0u;
  }

  // prologue: stage chunks 0,1
  STAGE(0, 0, 0);
  STAGE(0, 1, 1);

  // main: 5 superblocks x 3 citers (buffer phase repeats every 3 citers)
  int ci = 0;
  for (int sb = 0; sb < 5; ++sb) {
    ZERO_ACC();
    CHUNK(0, 0, ci, 2, 2) CHUNK(1, 1, ci, 3, 0)
    CHUNK(2, 2, ci + 1, 0, 1) CHUNK(3, 0, ci + 1, 1, 2) EPI(ci); ++ci;
    ZERO_ACC();
    CHUNK(0, 1, ci, 2, 0) CHUNK(1, 2, ci, 3, 1)
    CHUNK(2, 0, ci + 1, 0, 2) CHUNK(3, 1, ci + 1, 1, 0) EPI(ci); ++ci;
    ZERO_ACC();
    CHUNK(0, 2, ci, 2, 1) CHUNK(1, 0, ci, 3, 2)
    CHUNK(2, 1, ci + 1, 0, 0) CHUNK(3, 2, ci + 1, 1, 1) EPI(ci); ++ci;
  }
  // tail citer 15 (phase A): stages for its own chunks 2,3 then drain
  ZERO_ACC();
  CHUNK(0, 0, 15, 2, 2) CHUNK(1, 1, 15, 3, 0)
  CHUNK_V4(2, 2) CHUNK_V0(3, 0) EPI(15);

  // ---- block end: top-2 butterfly over l15 lanes, wc-merge, plain store ----
#pragma unroll
  for (int mi = 0; mi < 2; ++mi)
#pragma unroll
    for (int q = 0; q < 4; ++q) {
      const int s = mi * 4 + q;
      unsigned long long p0 =
          ((unsigned long long)enc_f32(-2.0f * b0v[s]) << 32) | b0c[s];
      unsigned long long p1 =
          ((unsigned long long)enc_f32(-2.0f * b1v[s]) << 32) | b1c[s];
#pragma unroll
      for (int off = 1; off < 16; off <<= 1) {
        const unsigned long long o0 = __shfl_xor(p0, off);
        const unsigned long long o1 = __shfl_xor(p1, off);
        const unsigned long long hi = p0 > o0 ? p0 : o0;
        p0 = umin64(p0, o0);
        p1 = umin64(hi, umin64(p1, o1));
      }
      if (l15 == 0) {
        const int rloc = wr * 32 + mi * 16 + l4 * 4 + q;
        top_sh[rloc][wc][0] = p0;
        top_sh[rloc][wc][1] = p1;
      }
    }
  __syncthreads();
  if (tid < BROWS) {
    const unsigned long long a0 = top_sh[tid][0][0], a1 = top_sh[tid][0][1];
    const unsigned long long c0 = top_sh[tid][1][0], c1 = top_sh[tid][1][1];
    const unsigned long long hi = a0 > c0 ? a0 : c0;
    ptop[(size_t)(row0 + tid) * 8 + panel * 2 + 0] = umin64(a0, c0);
    ptop[(size_t)(row0 + tid) * 8 + panel * 2 + 1] = umin64(hi, umin64(a1, c1));
  }
#undef STAGE
#undef COMPUTE
#undef CHUNK
#undef CHUNK_V4
#undef CHUNK_V0
#undef ZERO_ACC
#undef EPI
}

// ---- kernel 3: parallel fp64 refine (8 fixed candidates) + gather + loss ----
// wave per row; 8 lane-groups of 8 each score one candidate concurrently.
// NO cross-block signaling / fences (round-6 lesson).
__global__ __launch_bounds__(256) void k_refine_out(
    const float* __restrict__ z, const float* __restrict__ cb,
    const double* __restrict__ c2d, const unsigned long long* __restrict__ ptop,
    float* __restrict__ out, double* __restrict__ lossSlots) {
  const int w = threadIdx.x >> 6;
  const int lane = threadIdx.x & 63;
  const int r = blockIdx.x * 4 + w;
  const int g = lane >> 3;     // candidate slot 0..7 ([panel][2])
  const int u = lane & 7;

  const uint32_t jg =
      (uint32_t)(ptop[(size_t)r * 8 + g] & 0xFFFFFFFFull);

  // fp64 partial dot: lane covers elems [u*32, u*32+32)
  const float* zrow = z + (size_t)r * DIM;
  const float* crow = cb + (size_t)jg * DIM;
  double acc = 0.0;
#pragma unroll
  for (int t = 0; t < 8; ++t) {
    const float4 zv4 = *reinterpret_cast<const float4*>(zrow + u * 32 + t * 4);
    const float4 cv4 = *reinterpret_cast<const float4*>(crow + u * 32 + t * 4);
    acc += (double)zv4.x * cv4.x + (double)zv4.y * cv4.y +
           (double)zv4.z * cv4.z + (double)zv4.w * cv4.w;
  }
#pragma unroll
  for (int off = 1; off < 8; off <<= 1) acc += __shfl_xor(acc, off);
  // group leaders hold exact scores; cross-group argmin with lowest-j ties
  double s = (u == 0) ? (c2d[jg] - 2.0 * acc) : 1e300;
  uint32_t jj = (u == 0) ? jg : 0xFFFFFFFFu;
#pragma unroll
  for (int off = 8; off < 64; off <<= 1) {
    const double s2 = __shfl_xor(s, off);
    const uint32_t j2 = __shfl_xor(jj, off);
    if (s2 < s || (s2 == s && j2 < jj)) { s = s2; jj = j2; }
  }
  const uint32_t bestJ = __shfl(jj, 0);

  // gather z_q, write out, fp64 loss partial
  const float4 zv = *reinterpret_cast<const float4*>(zrow + lane * 4);
  const float4 q = *reinterpret_cast<const float4*>(
      cb + (size_t)bestJ * DIM + lane * 4);
  *reinterpret_cast<float4*>(out + (size_t)r * DIM + lane * 4) = q;
  const float dx = zv.x - q.x, dy = zv.y - q.y, dz = zv.z - q.z, dw = zv.w - q.w;
  double v = (double)dx * dx + (double)dy * dy + (double)dz * dz + (double)dw * dw;
#pragma unroll
  for (int off = 32; off > 0; off >>= 1) v += __shfl_xor(v, off);
  if (lane == 0) atomicAdd(&lossSlots[r & 255], v);
}

// ---- kernel 4: finalize loss (separate launch; kernel boundary = sync) ----
__global__ __launch_bounds__(256) void k_fin(const double* __restrict__ slots,
                                             float* __restrict__ out) {
  const int w = threadIdx.x >> 6, lane = threadIdx.x & 63;
  double v = slots[threadIdx.x];
#pragma unroll
  for (int off = 32; off > 0; off >>= 1) v += __shfl_xor(v, off);
  __shared__ double part[4];
  if (lane == 0) part[w] = v;
  __syncthreads();
  if (threadIdx.x == 0) {
    const double mse =
        (part[0] + part[1] + part[2] + part[3]) / (double)((size_t)NROWS * DIM);
    out[(size_t)NROWS * DIM] = (float)(1.1 * mse);   // 0.1*mse + mse
  }
}

extern "C" void kernel_launch(void* const* d_in, const int* in_sizes, int n_in,
                              void* d_out, int out_size, void* d_ws, size_t ws_size,
                              hipStream_t stream) {
  const float* z  = (const float*)d_in[0];
  const float* cb = (const float*)d_in[1];
  float* out = (float*)d_out;
  char* ws = (char*)d_ws;
  double* c2d = (double*)(ws + OFF_C2D);
  unsigned long long* ptop = (unsigned long long*)(ws + OFF_PTOP);
  double* lossSlots = (double*)(ws + OFF_LSLOT);
  unsigned short* z16  = (unsigned short*)(ws + OFF_Z16);
  unsigned short* cb16 = (unsigned short*)(ws + OFF_CB16);

  hipLaunchKernelGGL(k_prep, dim3(4096 + 2048 + 1), dim3(256), 0, stream,
                     z, cb, z16, cb16, c2d, lossSlots);
  hipLaunchKernelGGL(k_score, dim3((NROWS / BROWS) * (NCODES / PCOLS)),
                     dim3(256), 0, stream, z16, cb16, ptop);
  hipLaunchKernelGGL(k_refine_out, dim3(NROWS / 4), dim3(256), 0, stream,
                     z, cb, c2d, ptop, out, lossSlots);
  hipLaunchKernelGGL(k_fin, dim3(1), dim3(256), 0, stream, lossSlots, out);
}